// Round 13
// baseline (1196.012 us; speedup 1.0000x reference)
//
#include <hip/hip_runtime.h>

#define B_ 128
#define T_ 512
#define D_ 512
#define H_ 64
#define N3 192   // 3*H

#if __has_builtin(__builtin_amdgcn_rcpf)
#define RCP(x) __builtin_amdgcn_rcpf(x)
#else
#define RCP(x) (1.0f / (x))
#endif

typedef _Float16 h2v __attribute__((ext_vector_type(2)));

__device__ __forceinline__ float sigm_f(float x) {
  return RCP(1.0f + __expf(-x));
}
__device__ __forceinline__ float tanh_f(float x) {
  float e = __expf(-2.0f * fabsf(x));
  float t = (1.0f - e) * RCP(1.0f + e);
  return copysignf(t, x);
}

// 8-MAC f16 dot: weight chunk (int4 = 8 f16) x h chunk (int4 = 8 f16),
// f32 accumulation into two chains via v_dot2_f32_f16.
__device__ __forceinline__ void dot4acc(int4 w, int4 h, float& s0, float& s1) {
  s0 = __builtin_amdgcn_fdot2(__builtin_bit_cast(h2v, w.x),
                              __builtin_bit_cast(h2v, h.x), s0, false);
  s1 = __builtin_amdgcn_fdot2(__builtin_bit_cast(h2v, w.y),
                              __builtin_bit_cast(h2v, h.y), s1, false);
  s0 = __builtin_amdgcn_fdot2(__builtin_bit_cast(h2v, w.z),
                              __builtin_bit_cast(h2v, h.z), s0, false);
  s1 = __builtin_amdgcn_fdot2(__builtin_bit_cast(h2v, w.w),
                              __builtin_bit_cast(h2v, h.w), s1, false);
}

// ---------------- pass 1: gi0 = x @ W0ih^T + b0ih, plus act[t] flags ----------------
__global__ __launch_bounds__(256) void gemm_kernel(
    const float* __restrict__ x,     // [B,T,D]
    const float* __restrict__ w0ih,  // [N3,D]
    const float* __restrict__ b0ih,  // [N3]
    float* __restrict__ gi0,         // [B,Tc,N3]
    int* __restrict__ act,           // [T]
    int t0, int Tc) {
  __shared__ float Xs[64][33];
  __shared__ float Ws[64][33];
  __shared__ unsigned char sflag[64];

  int tid = threadIdx.x;
  int tpc = Tc >> 6;
  int b  = blockIdx.x / tpc;
  int tt = blockIdx.x % tpc;
  int c0 = blockIdx.y * 64;

  int tx = tid & 15, ty = tid >> 4;
  int r1  = tid >> 3;   // [0,32)
  int kc1 = tid & 7;    // [0,8)

  const float* xbase = x + ((size_t)b * T_ + t0 + tt * 64) * D_;
  const float* wbase = w0ih + (size_t)c0 * D_;

  float acc[4][4];
#pragma unroll
  for (int i = 0; i < 4; i++)
#pragma unroll
    for (int q = 0; q < 4; q++) acc[i][q] = 0.0f;

  bool f1 = false, f2 = false;

  for (int kt = 0; kt < D_ / 32; ++kt) {
    float4 va = *(const float4*)&xbase[(size_t)r1 * D_ + kt * 32 + kc1 * 4];
    float4 vb = *(const float4*)&xbase[(size_t)(r1 + 32) * D_ + kt * 32 + kc1 * 4];
    float4 wa = *(const float4*)&wbase[(size_t)r1 * D_ + kt * 32 + kc1 * 4];
    float4 wb = *(const float4*)&wbase[(size_t)(r1 + 32) * D_ + kt * 32 + kc1 * 4];
    f1 |= (va.x != 0.0f) | (va.y != 0.0f) | (va.z != 0.0f) | (va.w != 0.0f);
    f2 |= (vb.x != 0.0f) | (vb.y != 0.0f) | (vb.z != 0.0f) | (vb.w != 0.0f);
    __syncthreads();
    Xs[r1][kc1 * 4 + 0] = va.x; Xs[r1][kc1 * 4 + 1] = va.y;
    Xs[r1][kc1 * 4 + 2] = va.z; Xs[r1][kc1 * 4 + 3] = va.w;
    Xs[r1 + 32][kc1 * 4 + 0] = vb.x; Xs[r1 + 32][kc1 * 4 + 1] = vb.y;
    Xs[r1 + 32][kc1 * 4 + 2] = vb.z; Xs[r1 + 32][kc1 * 4 + 3] = vb.w;
    Ws[r1][kc1 * 4 + 0] = wa.x; Ws[r1][kc1 * 4 + 1] = wa.y;
    Ws[r1][kc1 * 4 + 2] = wa.z; Ws[r1][kc1 * 4 + 3] = wa.w;
    Ws[r1 + 32][kc1 * 4 + 0] = wb.x; Ws[r1 + 32][kc1 * 4 + 1] = wb.y;
    Ws[r1 + 32][kc1 * 4 + 2] = wb.z; Ws[r1 + 32][kc1 * 4 + 3] = wb.w;
    __syncthreads();
#pragma unroll
    for (int k = 0; k < 32; ++k) {
      float a_[4], b_[4];
#pragma unroll
      for (int i = 0; i < 4; i++) a_[i] = Xs[ty * 4 + i][k];
#pragma unroll
      for (int q = 0; q < 4; q++) b_[q] = Ws[tx * 4 + q][k];
#pragma unroll
      for (int i = 0; i < 4; i++)
#pragma unroll
        for (int q = 0; q < 4; q++) acc[i][q] = fmaf(a_[i], b_[q], acc[i][q]);
    }
  }

  float4 bias = *(const float4*)&b0ih[c0 + tx * 4];
#pragma unroll
  for (int i = 0; i < 4; i++) {
    int tloc = tt * 64 + ty * 4 + i;
    float4 o;
    o.x = acc[i][0] + bias.x;
    o.y = acc[i][1] + bias.y;
    o.z = acc[i][2] + bias.z;
    o.w = acc[i][3] + bias.w;
    *(float4*)&gi0[((size_t)b * Tc + tloc) * N3 + c0 + tx * 4] = o;
  }

  if (tid < 64) sflag[tid] = 0;
  __syncthreads();
  if (f1) sflag[r1] = 1;
  if (f2) sflag[r1 + 32] = 1;
  __syncthreads();
  if (tid < 64 && sflag[tid]) act[t0 + tt * 64 + tid] = 1;
}

// ---------------- pass 2: sequential scan, ONE WAVE (64 thr) per batch row ----------------
// Round-13 redesign. r10/11/12 established: memory is clean (0 conflicts, no
// spills) yet ~2000 cyc/step of the 3120 observed is multi-wave barrier stall
// (8 waves lockstepping 2 barriers/step). Single-wave block: __syncthreads()
// degenerates to a waitcnt + trivially-satisfied s_barrier, and program order
// = execution order, so the entire race/hoisting discipline disappears.
// Lane jj owns unit jj and computes FULL 64-wide dots (no reduction):
// 15 rows/step x 32 v_dot2_f32_f16. All 5 matrices in f16 LDS (120KB),
// chunk-XOR swizzled (phys chunk = c ^ (row&7)) -> the 64-lane row-strided
// b128 read is the 8-sweep minimum, no conflicts (r10-verified layout).
// h exchange: ds_write_b16 per lane + broadcast b128 reads (all lanes same
// addr = free). State f32 in registers; f16 only as dot inputs (r12 numerics,
// absmax 0.00195).
__global__ __launch_bounds__(64) void scan_kernel(
    const float* __restrict__ gi0,   // [B,Tc,N3]
    const float* __restrict__ w0hh, const float* __restrict__ w1ih,
    const float* __restrict__ w1hh, const float* __restrict__ w2ih,
    const float* __restrict__ w2hh,
    const float* __restrict__ b0hh, const float* __restrict__ b1ih,
    const float* __restrict__ b1hh, const float* __restrict__ b2ih,
    const float* __restrict__ b2hh,
    const int* __restrict__ act,     // [T]
    float* __restrict__ hstate,      // [3,B,H]
    float* __restrict__ out,         // [B,T,H]
    int t0, int Tc) {
  const int b  = blockIdx.x;
  const int jj = threadIdx.x;        // unit id [0,64)
  const int sw = jj & 7;             // swizzle key (row&7 == jj&7 for own rows)

  // s_w[m][row][chunk]: m 0=W0hh,1=W1ih,2=W1hh,3=W2ih,4=W2hh; 16B chunk =
  // 8 f16 cols; physical chunk = logical ^ (row&7).
  __shared__ __align__(16) int4 s_w[5][192][8];      // 122880 B
  __shared__ __align__(16) _Float16 s_h[3][H_];      // 384 B
  __shared__ int s_act[T_];

  // ---- one-time: f16-pack all weights into swizzled LDS ----
  {
    const float* wsrc[5] = {w0hh, w1ih, w1hh, w2ih, w2hh};
    for (int i = jj; i < 5 * 192 * 8; i += 64) {
      int m = i / 1536;
      int rem = i - m * 1536;
      int row = rem >> 3;
      int c = rem & 7;
      const float* sp = wsrc[m] + (size_t)row * H_ + 8 * c;
      float4 lo = *(const float4*)sp;
      float4 hi = *(const float4*)(sp + 4);
      h2v p0 = {(_Float16)lo.x, (_Float16)lo.y};
      h2v p1 = {(_Float16)lo.z, (_Float16)lo.w};
      h2v p2 = {(_Float16)hi.x, (_Float16)hi.y};
      h2v p3 = {(_Float16)hi.z, (_Float16)hi.w};
      int4 pk;
      pk.x = __builtin_bit_cast(int, p0);
      pk.y = __builtin_bit_cast(int, p1);
      pk.z = __builtin_bit_cast(int, p2);
      pk.w = __builtin_bit_cast(int, p3);
      s_w[m][row][c ^ (row & 7)] = pk;
    }
  }

  // ---- biases for this lane's 15 rows ----
  float bs[15];   // index m*3+r, m: 0=b0hh,1=b1ih,2=b1hh,3=b2ih,4=b2hh
  {
    const float* bp[5] = {b0hh, b1ih, b1hh, b2ih, b2hh};
#pragma unroll
    for (int m = 0; m < 5; m++)
#pragma unroll
      for (int r = 0; r < 3; r++) bs[m * 3 + r] = bp[m][jj + 64 * r];
  }

  // ---- h state: f32 regs (lane-owned) + f16 LDS copy ----
  float h0, h1, h2;
  if (t0 == 0) {
    h0 = 0.0f; h1 = 0.0f; h2 = 0.0f;
  } else {
    h0 = hstate[0 * B_ * H_ + b * H_ + jj];
    h1 = hstate[1 * B_ * H_ + b * H_ + jj];
    h2 = hstate[2 * B_ * H_ + b * H_ + jj];
  }
  s_h[0][jj] = (_Float16)h0;
  s_h[1][jj] = (_Float16)h1;
  s_h[2][jj] = (_Float16)h2;
  for (int i = jj; i < Tc; i += 64) s_act[i] = act[t0 + i];
  __syncthreads();

  const float* gibase = gi0 + (size_t)b * Tc * N3;
  float giR = gibase[jj], giZ = gibase[jj + 64], giN = gibase[jj + 128];

  const int4* h0p = (const int4*)s_h[0];
  const int4* h1p = (const int4*)s_h[1];
  const int4* h2p = (const int4*)s_h[2];

  for (int t = 0; t < Tc; ++t) {
    // prefetch next step's gi
    int tn = (t + 1 < Tc) ? t + 1 : t;
    const float* gin = gibase + (size_t)tn * N3;
    float nR = gin[jj], nZ = gin[jj + 64], nN = gin[jj + 128];

    const bool a = (s_act[t] != 0);

    // ---- phase 0: W0hh rows . h0  and  W1hh rows . h1 (6 full dots) ----
    float aR0 = 0, aR1 = 0, aZ0 = 0, aZ1 = 0, aN0 = 0, aN1 = 0;
    float cR0 = 0, cR1 = 0, cZ0 = 0, cZ1 = 0, cN0 = 0, cN1 = 0;
#pragma unroll
    for (int c = 0; c < 8; ++c) {
      int4 hx = h0p[c];
      int4 hy = h1p[c];
      int pc = c ^ sw;
      dot4acc(s_w[0][jj][pc],        hx, aR0, aR1);
      dot4acc(s_w[0][jj + 64][pc],   hx, aZ0, aZ1);
      dot4acc(s_w[0][jj + 128][pc],  hx, aN0, aN1);
      dot4acc(s_w[2][jj][pc],        hy, cR0, cR1);
      dot4acc(s_w[2][jj + 64][pc],   hy, cZ0, cZ1);
      dot4acc(s_w[2][jj + 128][pc],  hy, cN0, cN1);
    }
    float dR = aR0 + aR1 + bs[0];
    float dZ = aZ0 + aZ1 + bs[1];
    float dN = aN0 + aN1 + bs[2];
    float hR1 = cR0 + cR1 + bs[6];
    float hZ1 = cZ0 + cZ1 + bs[7];
    float hN1 = cN0 + cN1 + bs[8];

    // ---- gate 0 ----
    {
      float r = sigm_f(giR + dR);
      float z = sigm_f(giZ + dZ);
      float n = tanh_f(giN + r * dN);
      float hn = (1.0f - z) * n + z * h0;
      h0 = a ? hn : h0;
    }
    s_h[0][jj] = (_Float16)h0;   // phase-0 reads of s_h[0] are done (program order)
    __syncthreads();             // 1 wave: waitcnt + trivial s_barrier

    // ---- phase 1: W1ih rows . h0new (3 full dots) ; gate 1 ----
    {
      float eR0 = 0, eR1 = 0, eZ0 = 0, eZ1 = 0, eN0 = 0, eN1 = 0;
#pragma unroll
      for (int c = 0; c < 8; ++c) {
        int4 hx = h0p[c];
        int pc = c ^ sw;
        dot4acc(s_w[1][jj][pc],       hx, eR0, eR1);
        dot4acc(s_w[1][jj + 64][pc],  hx, eZ0, eZ1);
        dot4acc(s_w[1][jj + 128][pc], hx, eN0, eN1);
      }
      float iR = eR0 + eR1 + bs[3];
      float iZ = eZ0 + eZ1 + bs[4];
      float iN = eN0 + eN1 + bs[5];
      float r = sigm_f(iR + hR1);
      float z = sigm_f(iZ + hZ1);
      float n = tanh_f(iN + r * hN1);
      float hn = (1.0f - z) * n + z * h1;
      h1 = a ? hn : h1;
    }
    s_h[1][jj] = (_Float16)h1;
    __syncthreads();

    // ---- phase 2: W2ih rows . h1new and W2hh rows . h2 (6 dots); gate 2 ----
    {
      float fR0 = 0, fR1 = 0, fZ0 = 0, fZ1 = 0, fN0 = 0, fN1 = 0;
      float kR0 = 0, kR1 = 0, kZ0 = 0, kZ1 = 0, kN0 = 0, kN1 = 0;
#pragma unroll
      for (int c = 0; c < 8; ++c) {
        int4 hx = h1p[c];
        int4 hy = h2p[c];
        int pc = c ^ sw;
        dot4acc(s_w[3][jj][pc],        hx, fR0, fR1);
        dot4acc(s_w[3][jj + 64][pc],   hx, fZ0, fZ1);
        dot4acc(s_w[3][jj + 128][pc],  hx, fN0, fN1);
        dot4acc(s_w[4][jj][pc],        hy, kR0, kR1);
        dot4acc(s_w[4][jj + 64][pc],   hy, kZ0, kZ1);
        dot4acc(s_w[4][jj + 128][pc],  hy, kN0, kN1);
      }
      float jR = fR0 + fR1 + bs[9];
      float jZ = fZ0 + fZ1 + bs[10];
      float jN = fN0 + fN1 + bs[11];
      float kR = kR0 + kR1 + bs[12];
      float kZ = kZ0 + kZ1 + bs[13];
      float kN = kN0 + kN1 + bs[14];
      float r = sigm_f(jR + kR);
      float z = sigm_f(jZ + kZ);
      float n = tanh_f(jN + r * kN);
      float hn = (1.0f - z) * n + z * h2;
      h2 = a ? hn : h2;
    }
    s_h[2][jj] = (_Float16)h2;   // next read of s_h[2] is next step's phase 2
                                 // -> behind two syncs
    out[((size_t)b * T_ + t0 + t) * H_ + jj] = a ? h2 : 0.0f;  // 256B coalesced

    giR = nR; giZ = nZ; giN = nN;
    // no end-of-step barrier needed: next phase-0 reads s_h[0]/s_h[1], whose
    // writes were drained by this step's two syncs.
  }

  hstate[0 * B_ * H_ + b * H_ + jj] = h0;
  hstate[1 * B_ * H_ + b * H_ + jj] = h1;
  hstate[2 * B_ * H_ + b * H_ + jj] = h2;
}

extern "C" void kernel_launch(void* const* d_in, const int* in_sizes, int n_in,
                              void* d_out, int out_size, void* d_ws, size_t ws_size,
                              hipStream_t stream) {
  const float* x    = (const float*)d_in[0];
  const float* w0ih = (const float*)d_in[1];
  const float* w0hh = (const float*)d_in[2];
  const float* b0ih = (const float*)d_in[3];
  const float* b0hh = (const float*)d_in[4];
  const float* w1ih = (const float*)d_in[5];
  const float* w1hh = (const float*)d_in[6];
  const float* b1ih = (const float*)d_in[7];
  const float* b1hh = (const float*)d_in[8];
  const float* w2ih = (const float*)d_in[9];
  const float* w2hh = (const float*)d_in[10];
  const float* b2ih = (const float*)d_in[11];
  const float* b2hh = (const float*)d_in[12];
  float* out = (float*)d_out;

  char* p = (char*)d_ws;
  int* act      = (int*)p;    p += 4096;
  float* hstate = (float*)p;  p += (size_t)3 * B_ * H_ * 4;
  size_t fixed = (size_t)(p - (char*)d_ws);

  int Tc = T_;
  while (Tc > 64 && fixed + (size_t)B_ * Tc * N3 * 4 > ws_size) Tc >>= 1;
  float* gi0 = (float*)p;

  hipMemsetAsync(act, 0, T_ * sizeof(int), stream);
  for (int t0 = 0; t0 < T_; t0 += Tc) {
    gemm_kernel<<<dim3(B_ * (Tc / 64), 3), 256, 0, stream>>>(
        x, w0ih, b0ih, gi0, act, t0, Tc);
    scan_kernel<<<B_, 64, 0, stream>>>(
        gi0, w0hh, w1ih, w1hh, w2ih, w2hh,
        b0hh, b1ih, b1hh, b2ih, b2hh, act, hstate, out, t0, Tc);
  }
}

// Round 14
// 626.513 us; speedup vs baseline: 1.9090x; 1.9090x over previous
//
#include <hip/hip_runtime.h>

#define B_ 128
#define T_ 512
#define D_ 512
#define H_ 64
#define N3 192   // 3*H

#if __has_builtin(__builtin_amdgcn_rcpf)
#define RCP(x) __builtin_amdgcn_rcpf(x)
#else
#define RCP(x) (1.0f / (x))
#endif

typedef _Float16 h2v __attribute__((ext_vector_type(2)));

__device__ __forceinline__ float sigm_f(float x) {
  return RCP(1.0f + __expf(-x));
}
__device__ __forceinline__ float tanh_f(float x) {
  float e = __expf(-2.0f * fabsf(x));
  float t = (1.0f - e) * RCP(1.0f + e);
  return copysignf(t, x);
}

// DPP lane-group sums (bound_ctrl=1). Lane layout guarantees the group is
// xor-adjacent: red2 over lane pairs (0xB1 = quad_perm[1,0,3,2]),
// red4 over quads (0xB1 then 0x4E = quad_perm[2,3,0,1]).
template <int CTRL>
__device__ __forceinline__ float dpp_add(float v) {
  int t = __builtin_amdgcn_update_dpp(0, __float_as_int(v), CTRL, 0xF, 0xF, true);
  return v + __int_as_float(t);
}
__device__ __forceinline__ float red2(float v) { return dpp_add<0xB1>(v); }
__device__ __forceinline__ float red4(float v) {
  v = dpp_add<0xB1>(v);
  v = dpp_add<0x4E>(v);
  return v;
}

// 8-MAC f16 dot: weight chunk (int4 = 8 f16) x h chunk, f32 accum, 2 chains.
__device__ __forceinline__ void dot4acc(int4 w, int4 h, float& s0, float& s1) {
  s0 = __builtin_amdgcn_fdot2(__builtin_bit_cast(h2v, w.x),
                              __builtin_bit_cast(h2v, h.x), s0, false);
  s1 = __builtin_amdgcn_fdot2(__builtin_bit_cast(h2v, w.y),
                              __builtin_bit_cast(h2v, h.y), s1, false);
  s0 = __builtin_amdgcn_fdot2(__builtin_bit_cast(h2v, w.z),
                              __builtin_bit_cast(h2v, h.z), s0, false);
  s1 = __builtin_amdgcn_fdot2(__builtin_bit_cast(h2v, w.w),
                              __builtin_bit_cast(h2v, h.w), s1, false);
}
// 16-MAC dot from 8 register dwords x two h chunks.
__device__ __forceinline__ void dot8reg(const int* w, int4 a, int4 b,
                                        float& s0, float& s1) {
  s0 = __builtin_amdgcn_fdot2(__builtin_bit_cast(h2v, w[0]),
                              __builtin_bit_cast(h2v, a.x), s0, false);
  s1 = __builtin_amdgcn_fdot2(__builtin_bit_cast(h2v, w[1]),
                              __builtin_bit_cast(h2v, a.y), s1, false);
  s0 = __builtin_amdgcn_fdot2(__builtin_bit_cast(h2v, w[2]),
                              __builtin_bit_cast(h2v, a.z), s0, false);
  s1 = __builtin_amdgcn_fdot2(__builtin_bit_cast(h2v, w[3]),
                              __builtin_bit_cast(h2v, a.w), s1, false);
  s0 = __builtin_amdgcn_fdot2(__builtin_bit_cast(h2v, w[4]),
                              __builtin_bit_cast(h2v, b.x), s0, false);
  s1 = __builtin_amdgcn_fdot2(__builtin_bit_cast(h2v, w[5]),
                              __builtin_bit_cast(h2v, b.y), s1, false);
  s0 = __builtin_amdgcn_fdot2(__builtin_bit_cast(h2v, w[6]),
                              __builtin_bit_cast(h2v, b.z), s0, false);
  s1 = __builtin_amdgcn_fdot2(__builtin_bit_cast(h2v, w[7]),
                              __builtin_bit_cast(h2v, b.w), s1, false);
}

#define KEEP(x) asm volatile("" : "+v"(x))

// ---------------- pass 1: gi0 = x @ W0ih^T + b0ih, plus act[t] flags ----------------
__global__ __launch_bounds__(256) void gemm_kernel(
    const float* __restrict__ x,     // [B,T,D]
    const float* __restrict__ w0ih,  // [N3,D]
    const float* __restrict__ b0ih,  // [N3]
    float* __restrict__ gi0,         // [B,Tc,N3]
    int* __restrict__ act,           // [T]
    int t0, int Tc) {
  __shared__ float Xs[64][33];
  __shared__ float Ws[64][33];
  __shared__ unsigned char sflag[64];

  int tid = threadIdx.x;
  int tpc = Tc >> 6;
  int b  = blockIdx.x / tpc;
  int tt = blockIdx.x % tpc;
  int c0 = blockIdx.y * 64;

  int tx = tid & 15, ty = tid >> 4;
  int r1  = tid >> 3;   // [0,32)
  int kc1 = tid & 7;    // [0,8)

  const float* xbase = x + ((size_t)b * T_ + t0 + tt * 64) * D_;
  const float* wbase = w0ih + (size_t)c0 * D_;

  float acc[4][4];
#pragma unroll
  for (int i = 0; i < 4; i++)
#pragma unroll
    for (int q = 0; q < 4; q++) acc[i][q] = 0.0f;

  bool f1 = false, f2 = false;

  for (int kt = 0; kt < D_ / 32; ++kt) {
    float4 va = *(const float4*)&xbase[(size_t)r1 * D_ + kt * 32 + kc1 * 4];
    float4 vb = *(const float4*)&xbase[(size_t)(r1 + 32) * D_ + kt * 32 + kc1 * 4];
    float4 wa = *(const float4*)&wbase[(size_t)r1 * D_ + kt * 32 + kc1 * 4];
    float4 wb = *(const float4*)&wbase[(size_t)(r1 + 32) * D_ + kt * 32 + kc1 * 4];
    f1 |= (va.x != 0.0f) | (va.y != 0.0f) | (va.z != 0.0f) | (va.w != 0.0f);
    f2 |= (vb.x != 0.0f) | (vb.y != 0.0f) | (vb.z != 0.0f) | (vb.w != 0.0f);
    __syncthreads();
    Xs[r1][kc1 * 4 + 0] = va.x; Xs[r1][kc1 * 4 + 1] = va.y;
    Xs[r1][kc1 * 4 + 2] = va.z; Xs[r1][kc1 * 4 + 3] = va.w;
    Xs[r1 + 32][kc1 * 4 + 0] = vb.x; Xs[r1 + 32][kc1 * 4 + 1] = vb.y;
    Xs[r1 + 32][kc1 * 4 + 2] = vb.z; Xs[r1 + 32][kc1 * 4 + 3] = vb.w;
    Ws[r1][kc1 * 4 + 0] = wa.x; Ws[r1][kc1 * 4 + 1] = wa.y;
    Ws[r1][kc1 * 4 + 2] = wa.z; Ws[r1][kc1 * 4 + 3] = wa.w;
    Ws[r1 + 32][kc1 * 4 + 0] = wb.x; Ws[r1 + 32][kc1 * 4 + 1] = wb.y;
    Ws[r1 + 32][kc1 * 4 + 2] = wb.z; Ws[r1 + 32][kc1 * 4 + 3] = wb.w;
    __syncthreads();
#pragma unroll
    for (int k = 0; k < 32; ++k) {
      float a_[4], b_[4];
#pragma unroll
      for (int i = 0; i < 4; i++) a_[i] = Xs[ty * 4 + i][k];
#pragma unroll
      for (int q = 0; q < 4; q++) b_[q] = Ws[tx * 4 + q][k];
#pragma unroll
      for (int i = 0; i < 4; i++)
#pragma unroll
        for (int q = 0; q < 4; q++) acc[i][q] = fmaf(a_[i], b_[q], acc[i][q]);
    }
  }

  float4 bias = *(const float4*)&b0ih[c0 + tx * 4];
#pragma unroll
  for (int i = 0; i < 4; i++) {
    int tloc = tt * 64 + ty * 4 + i;
    float4 o;
    o.x = acc[i][0] + bias.x;
    o.y = acc[i][1] + bias.y;
    o.z = acc[i][2] + bias.z;
    o.w = acc[i][3] + bias.w;
    *(float4*)&gi0[((size_t)b * Tc + tloc) * N3 + c0 + tx * 4] = o;
  }

  if (tid < 64) sflag[tid] = 0;
  __syncthreads();
  if (f1) sflag[r1] = 1;
  if (f2) sflag[r1 + 32] = 1;
  __syncthreads();
  if (tid < 64 && sflag[tid]) act[t0 + tt * 64 + tid] = 1;
}

// ------------- pass 2: LAYER-PIPELINED scan, one WG (640 thr) per batch row -------------
// 10 waves, 3 groups: waves 0-1 = layer 0 (step i), waves 2-5 = layer 1
// (step i-1), waves 6-9 = layer 2 (step i-2). ONE barrier per pipeline tick.
// All h buffers double-buffered by tick parity: every read targets parity
// p^1 (written last tick), every write targets p -> single-barrier-safe.
// L0: (jj=lt>>1, gg=lt&1), 32-wide segments, red2. L1/L2: (jj=lt>>2, gg=lt&3),
// 16-wide, red4. hh-weights in f16 XOR-swizzled LDS (r12's measured-0-conflict
// pattern: 8 consecutive lanes cover 8 distinct chunk positions); ih-weights
// in registers (24+4 pinned dwords, inside the proven ~39-value budget).
// State f32 in regs; f16 only as dot inputs (r12 numerics, absmax 0.00195).
__global__ __launch_bounds__(640) void scan_kernel(
    const float* __restrict__ gi0,   // [B,Tc,N3]
    const float* __restrict__ w0hh, const float* __restrict__ w1ih,
    const float* __restrict__ w1hh, const float* __restrict__ w2ih,
    const float* __restrict__ w2hh,
    const float* __restrict__ b0hh, const float* __restrict__ b1ih,
    const float* __restrict__ b1hh, const float* __restrict__ b2ih,
    const float* __restrict__ b2hh,
    const int* __restrict__ act,     // [T]
    float* __restrict__ hstate,      // [3,B,H]
    float* __restrict__ out,         // [B,T,H]
    int t0, int Tc) {
  const int b   = blockIdx.x;
  const int tid = threadIdx.x;

  // s_w[m][row][chunk]: m 0=W0hh,1=W1hh,2=W2hh; 16B chunk = 8 f16 cols;
  // physical chunk = logical ^ (row&7).
  __shared__ __align__(16) int4 s_w[3][192][8];       // 73728 B
  __shared__ __align__(16) _Float16 s_h[3][2][H_];    // [layer][parity][unit]
  __shared__ int s_act[T_];

  // ---- one-time: f16-pack hh-weights into swizzled LDS ----
  {
    const float* wsrc[3] = {w0hh, w1hh, w2hh};
    for (int i = tid; i < 3 * 192 * 8; i += 640) {
      int m = i / 1536;
      int rem = i - m * 1536;
      int row = rem >> 3;
      int c = rem & 7;
      const float* sp = wsrc[m] + (size_t)row * H_ + 8 * c;
      float4 lo = *(const float4*)sp;
      float4 hi = *(const float4*)(sp + 4);
      h2v p0 = {(_Float16)lo.x, (_Float16)lo.y};
      h2v p1 = {(_Float16)lo.z, (_Float16)lo.w};
      h2v p2 = {(_Float16)hi.x, (_Float16)hi.y};
      h2v p3 = {(_Float16)hi.z, (_Float16)hi.w};
      int4 pk;
      pk.x = __builtin_bit_cast(int, p0);
      pk.y = __builtin_bit_cast(int, p1);
      pk.z = __builtin_bit_cast(int, p2);
      pk.w = __builtin_bit_cast(int, p3);
      s_w[m][row][c ^ (row & 7)] = pk;
    }
  }
  for (int i = tid; i < Tc; i += 640) s_act[i] = act[t0 + i];

  // ---- group decomposition (wave-aligned: waves 0-1 / 2-5 / 6-9) ----
  const int grp = (tid < 128) ? 0 : (tid < 384) ? 1 : 2;
  const int lt  = tid - ((grp == 0) ? 0 : (grp == 1) ? 128 : 384);
  const int jj  = (grp == 0) ? (lt >> 1) : (lt >> 2);
  const int gg  = (grp == 0) ? (lt & 1) : (lt & 3);
  const int swz = jj & 7;

  // ---- seed h (both parities) + register state ----
  if (tid < H_) {
    float v0 = (t0 == 0) ? 0.f : hstate[0 * B_ * H_ + b * H_ + tid];
    float v1 = (t0 == 0) ? 0.f : hstate[1 * B_ * H_ + b * H_ + tid];
    float v2 = (t0 == 0) ? 0.f : hstate[2 * B_ * H_ + b * H_ + tid];
    s_h[0][0][tid] = (_Float16)v0; s_h[0][1][tid] = (_Float16)v0;
    s_h[1][0][tid] = (_Float16)v1; s_h[1][1][tid] = (_Float16)v1;
    s_h[2][0][tid] = (_Float16)v2; s_h[2][1][tid] = (_Float16)v2;
  }
  float hreg = (t0 == 0) ? 0.f : hstate[grp * B_ * H_ + b * H_ + jj];

  // ---- register-resident ih-weights (L1: W1ih, L2: W2ih; L0 dummy) ----
  int rpk[3][8];
  {
    const float* ihsrc = (grp == 2) ? w2ih : w1ih;
    const int lg = (grp == 0) ? (gg * 2) : gg;   // L0 dummy, valid addrs
#pragma unroll
    for (int r = 0; r < 3; ++r) {
      const float* src = ihsrc + (size_t)(jj + 64 * r) * H_ + 16 * lg;
#pragma unroll
      for (int q = 0; q < 8; ++q) {
        float2 f = *(const float2*)(src + 2 * q);
        h2v pv = {(_Float16)f.x, (_Float16)f.y};
        rpk[r][q] = __builtin_bit_cast(int, pv);
      }
    }
#pragma unroll
    for (int r = 0; r < 3; ++r)
#pragma unroll
      for (int q = 0; q < 8; ++q) KEEP(rpk[r][q]);
  }

  // ---- biases: [0]=R combined, [1]=Z combined, [2]=ih_N, [3]=hh_N ----
  float bsv[4];
  if (grp == 0) {
    bsv[0] = b0hh[jj]; bsv[1] = b0hh[jj + 64]; bsv[2] = 0.f;
    bsv[3] = b0hh[jj + 128];
  } else if (grp == 1) {
    bsv[0] = b1ih[jj] + b1hh[jj];
    bsv[1] = b1ih[jj + 64] + b1hh[jj + 64];
    bsv[2] = b1ih[jj + 128]; bsv[3] = b1hh[jj + 128];
  } else {
    bsv[0] = b2ih[jj] + b2hh[jj];
    bsv[1] = b2ih[jj + 64] + b2hh[jj + 64];
    bsv[2] = b2ih[jj + 128]; bsv[3] = b2hh[jj + 128];
  }

  const float* gib = gi0 + (size_t)b * Tc * N3;
  float giR = 0.f, giZ = 0.f, giN = 0.f;
  if (grp == 0) { giR = gib[jj]; giZ = gib[jj + 64]; giN = gib[jj + 128]; }

  __syncthreads();

  // ---- pipeline: tick i computes L0(t=i), L1(t=i-1), L2(t=i-2) ----
  for (int i = 0; i < Tc + 2; ++i) {
    const int p = i & 1;
    if (grp == 0) {
      if (i < Tc) {
        const int4* hp = (const int4*)s_h[0][p ^ 1];
        int4 h0s = hp[4 * gg + 0], h1s = hp[4 * gg + 1];
        int4 h2s = hp[4 * gg + 2], h3s = hp[4 * gg + 3];
        float R0 = 0, R1 = 0, Z0 = 0, Z1 = 0, N0 = 0, N1 = 0;
#pragma unroll
        for (int k = 0; k < 4; ++k) {
          int pc = (4 * gg + k) ^ swz;
          int4 hk = (k == 0) ? h0s : (k == 1) ? h1s : (k == 2) ? h2s : h3s;
          dot4acc(s_w[0][jj][pc],       hk, R0, R1);
          dot4acc(s_w[0][jj + 64][pc],  hk, Z0, Z1);
          dot4acc(s_w[0][jj + 128][pc], hk, N0, N1);
        }
        float dR = red2(R0 + R1) + bsv[0];
        float dZ = red2(Z0 + Z1) + bsv[1];
        float dN = red2(N0 + N1) + bsv[3];
        bool a = (s_act[i] != 0);
        float r = sigm_f(giR + dR);
        float z = sigm_f(giZ + dZ);
        float n = tanh_f(giN + r * dN);
        float hn = (1.0f - z) * n + z * hreg;
        hreg = a ? hn : hreg;
        if (gg == 0) s_h[0][p][jj] = (_Float16)hreg;
        int tn = (i + 1 < Tc) ? i + 1 : i;   // prefetch next gi across barrier
        giR = gib[(size_t)tn * N3 + jj];
        giZ = gib[(size_t)tn * N3 + jj + 64];
        giN = gib[(size_t)tn * N3 + jj + 128];
      }
    } else if (grp == 1) {
      if (i >= 1 && i <= Tc) {
        const int4* h0p = (const int4*)s_h[0][p ^ 1];
        const int4* h1p = (const int4*)s_h[1][p ^ 1];
        int4 x0 = h0p[2 * gg], x1 = h0p[2 * gg + 1];
        int4 y0 = h1p[2 * gg], y1 = h1p[2 * gg + 1];
        float vR0 = 0, vR1 = 0, vZ0 = 0, vZ1 = 0;
        float iN0 = 0, iN1 = 0, hN0 = 0, hN1 = 0;
        dot8reg(rpk[0], x0, x1, vR0, vR1);
        dot8reg(rpk[1], x0, x1, vZ0, vZ1);
        dot8reg(rpk[2], x0, x1, iN0, iN1);
        int pc0 = (2 * gg) ^ swz, pc1 = (2 * gg + 1) ^ swz;
        dot4acc(s_w[1][jj][pc0],       y0, vR0, vR1);
        dot4acc(s_w[1][jj][pc1],       y1, vR0, vR1);
        dot4acc(s_w[1][jj + 64][pc0],  y0, vZ0, vZ1);
        dot4acc(s_w[1][jj + 64][pc1],  y1, vZ0, vZ1);
        dot4acc(s_w[1][jj + 128][pc0], y0, hN0, hN1);
        dot4acc(s_w[1][jj + 128][pc1], y1, hN0, hN1);
        float sR = red4(vR0 + vR1) + bsv[0];
        float sZ = red4(vZ0 + vZ1) + bsv[1];
        float iN = red4(iN0 + iN1) + bsv[2];
        float hN = red4(hN0 + hN1) + bsv[3];
        bool a = (s_act[i - 1] != 0);
        float r = sigm_f(sR);
        float z = sigm_f(sZ);
        float n = tanh_f(iN + r * hN);
        float hn = (1.0f - z) * n + z * hreg;
        hreg = a ? hn : hreg;
        if (gg == 0) s_h[1][p][jj] = (_Float16)hreg;
      }
    } else {
      if (i >= 2) {
        const int4* h1p = (const int4*)s_h[1][p ^ 1];
        const int4* h2p = (const int4*)s_h[2][p ^ 1];
        int4 x0 = h1p[2 * gg], x1 = h1p[2 * gg + 1];
        int4 y0 = h2p[2 * gg], y1 = h2p[2 * gg + 1];
        float vR0 = 0, vR1 = 0, vZ0 = 0, vZ1 = 0;
        float iN0 = 0, iN1 = 0, hN0 = 0, hN1 = 0;
        dot8reg(rpk[0], x0, x1, vR0, vR1);
        dot8reg(rpk[1], x0, x1, vZ0, vZ1);
        dot8reg(rpk[2], x0, x1, iN0, iN1);
        int pc0 = (2 * gg) ^ swz, pc1 = (2 * gg + 1) ^ swz;
        dot4acc(s_w[2][jj][pc0],       y0, vR0, vR1);
        dot4acc(s_w[2][jj][pc1],       y1, vR0, vR1);
        dot4acc(s_w[2][jj + 64][pc0],  y0, vZ0, vZ1);
        dot4acc(s_w[2][jj + 64][pc1],  y1, vZ0, vZ1);
        dot4acc(s_w[2][jj + 128][pc0], y0, hN0, hN1);
        dot4acc(s_w[2][jj + 128][pc1], y1, hN0, hN1);
        float sR = red4(vR0 + vR1) + bsv[0];
        float sZ = red4(vZ0 + vZ1) + bsv[1];
        float iN = red4(iN0 + iN1) + bsv[2];
        float hN = red4(hN0 + hN1) + bsv[3];
        bool a = (s_act[i - 2] != 0);
        float r = sigm_f(sR);
        float z = sigm_f(sZ);
        float n = tanh_f(iN + r * hN);
        float hn = (1.0f - z) * n + z * hreg;
        hreg = a ? hn : hreg;
        if (gg == 0) {
          s_h[2][p][jj] = (_Float16)hreg;
          out[((size_t)b * T_ + t0 + (i - 2)) * H_ + jj] = a ? hreg : 0.0f;
        }
      }
    }
    __syncthreads();   // the ONE barrier per tick
  }

  if (gg == 0) hstate[grp * B_ * H_ + b * H_ + jj] = hreg;
}

extern "C" void kernel_launch(void* const* d_in, const int* in_sizes, int n_in,
                              void* d_out, int out_size, void* d_ws, size_t ws_size,
                              hipStream_t stream) {
  const float* x    = (const float*)d_in[0];
  const float* w0ih = (const float*)d_in[1];
  const float* w0hh = (const float*)d_in[2];
  const float* b0ih = (const float*)d_in[3];
  const float* b0hh = (const float*)d_in[4];
  const float* w1ih = (const float*)d_in[5];
  const float* w1hh = (const float*)d_in[6];
  const float* b1ih = (const float*)d_in[7];
  const float* b1hh = (const float*)d_in[8];
  const float* w2ih = (const float*)d_in[9];
  const float* w2hh = (const float*)d_in[10];
  const float* b2ih = (const float*)d_in[11];
  const float* b2hh = (const float*)d_in[12];
  float* out = (float*)d_out;

  char* p = (char*)d_ws;
  int* act      = (int*)p;    p += 4096;
  float* hstate = (float*)p;  p += (size_t)3 * B_ * H_ * 4;
  size_t fixed = (size_t)(p - (char*)d_ws);

  int Tc = T_;
  while (Tc > 64 && fixed + (size_t)B_ * Tc * N3 * 4 > ws_size) Tc >>= 1;
  float* gi0 = (float*)p;

  hipMemsetAsync(act, 0, T_ * sizeof(int), stream);
  for (int t0 = 0; t0 < T_; t0 += Tc) {
    gemm_kernel<<<dim3(B_ * (Tc / 64), 3), 256, 0, stream>>>(
        x, w0ih, b0ih, gi0, act, t0, Tc);
    scan_kernel<<<B_, 640, 0, stream>>>(
        gi0, w0hh, w1ih, w1hh, w2ih, w2hh,
        b0hh, b1ih, b1hh, b2ih, b2hh, act, hstate, out, t0, Tc);
  }
}

// Round 15
// 449.104 us; speedup vs baseline: 2.6631x; 1.3950x over previous
//
#include <hip/hip_runtime.h>

#define B_ 128
#define T_ 512
#define D_ 512
#define H_ 64
#define N3 192   // 3*H

#if __has_builtin(__builtin_amdgcn_rcpf)
#define RCP(x) __builtin_amdgcn_rcpf(x)
#else
#define RCP(x) (1.0f / (x))
#endif

typedef _Float16 h2v __attribute__((ext_vector_type(2)));
typedef _Float16 f16x8 __attribute__((ext_vector_type(8)));
typedef float f32x4 __attribute__((ext_vector_type(4)));

__device__ __forceinline__ float sigm_f(float x) {
  return RCP(1.0f + __expf(-x));
}
__device__ __forceinline__ float tanh_f(float x) {
  float e = __expf(-2.0f * fabsf(x));
  float t = (1.0f - e) * RCP(1.0f + e);
  return copysignf(t, x);
}

template <int CTRL>
__device__ __forceinline__ float dpp_add(float v) {
  int t = __builtin_amdgcn_update_dpp(0, __float_as_int(v), CTRL, 0xF, 0xF, true);
  return v + __int_as_float(t);
}
__device__ __forceinline__ float red2(float v) { return dpp_add<0xB1>(v); }
__device__ __forceinline__ float red4(float v) {
  v = dpp_add<0xB1>(v);
  v = dpp_add<0x4E>(v);
  return v;
}

__device__ __forceinline__ void dot4acc(int4 w, int4 h, float& s0, float& s1) {
  s0 = __builtin_amdgcn_fdot2(__builtin_bit_cast(h2v, w.x),
                              __builtin_bit_cast(h2v, h.x), s0, false);
  s1 = __builtin_amdgcn_fdot2(__builtin_bit_cast(h2v, w.y),
                              __builtin_bit_cast(h2v, h.y), s1, false);
  s0 = __builtin_amdgcn_fdot2(__builtin_bit_cast(h2v, w.z),
                              __builtin_bit_cast(h2v, h.z), s0, false);
  s1 = __builtin_amdgcn_fdot2(__builtin_bit_cast(h2v, w.w),
                              __builtin_bit_cast(h2v, h.w), s1, false);
}
__device__ __forceinline__ void dot8reg(const int* w, int4 a, int4 b,
                                        float& s0, float& s1) {
  s0 = __builtin_amdgcn_fdot2(__builtin_bit_cast(h2v, w[0]),
                              __builtin_bit_cast(h2v, a.x), s0, false);
  s1 = __builtin_amdgcn_fdot2(__builtin_bit_cast(h2v, w[1]),
                              __builtin_bit_cast(h2v, a.y), s1, false);
  s0 = __builtin_amdgcn_fdot2(__builtin_bit_cast(h2v, w[2]),
                              __builtin_bit_cast(h2v, a.z), s0, false);
  s1 = __builtin_amdgcn_fdot2(__builtin_bit_cast(h2v, w[3]),
                              __builtin_bit_cast(h2v, a.w), s1, false);
  s0 = __builtin_amdgcn_fdot2(__builtin_bit_cast(h2v, w[4]),
                              __builtin_bit_cast(h2v, b.x), s0, false);
  s1 = __builtin_amdgcn_fdot2(__builtin_bit_cast(h2v, w[5]),
                              __builtin_bit_cast(h2v, b.y), s1, false);
  s0 = __builtin_amdgcn_fdot2(__builtin_bit_cast(h2v, w[6]),
                              __builtin_bit_cast(h2v, b.z), s0, false);
  s1 = __builtin_amdgcn_fdot2(__builtin_bit_cast(h2v, w[7]),
                              __builtin_bit_cast(h2v, b.w), s1, false);
}

#define KEEP(x) asm volatile("" : "+v"(x))

// ---------------- pass 1 (round-15 MFMA rewrite): gi0 = X @ W0ih^T + b0ih ----------------
// M = B*Tc rows, N3 cols, K = D. f16 inputs (converted during staging),
// f32 MFMA accumulation. 64x64 tile, 4 waves (2x2), each 32x32 via 2x2
// mfma_f32_16x16x32_f16 fragments, BK=64 (2 k-steps/iter, 8 iters).
// LDS rows padded to 72 f16 (144B): fragment-read banks = (row*4+g*4) mod 32
// -> 2-way max (free, m136). 1D grid, n-tile INNER so the 3 n-blocks sharing
// an X-tile are dispatch-adjacent (L2 reuse of the 3x X re-read).
// C/D layout (guide, m89-verified): col = lane&15, row = (lane>>4)*4 + reg.
__global__ __launch_bounds__(256) void gemm_kernel(
    const float* __restrict__ x,     // [B,T,D]
    const float* __restrict__ w0ih,  // [N3,D]
    const float* __restrict__ b0ih,  // [N3]
    float* __restrict__ gi0,         // [B,Tc,N3]
    int* __restrict__ act,           // [T]
    int t0, int Tc) {
  __shared__ _Float16 Xs[64][72];
  __shared__ _Float16 Ws[64][72];
  __shared__ unsigned char sflag[64];

  const int tid = threadIdx.x;
  const int bid = blockIdx.x;
  const int nt = bid % 3;
  const int mt = bid / 3;
  const int tpc = Tc >> 6;
  const int b  = mt / tpc;
  const int tt = mt % tpc;
  const int c0 = nt * 64;

  const int lane = tid & 63;
  const int wid  = tid >> 6;
  const int wm = (wid >> 1) * 32;
  const int wn = (wid & 1) * 32;
  const int l15 = lane & 15;
  const int l4  = lane >> 4;

  const float* xbase = x + ((size_t)b * T_ + t0 + tt * 64) * D_;
  const float* wbase = w0ih + (size_t)c0 * D_;

  // staging role: row = tid>>2, 16-col group = (tid&3)*16
  const int srow = tid >> 2;
  const int scg  = (tid & 3) << 4;
  const float* xrow = xbase + (size_t)srow * D_;
  const float* wrow = wbase + (size_t)srow * D_;

  f32x4 acc[2][2];
#pragma unroll
  for (int mi = 0; mi < 2; ++mi)
#pragma unroll
    for (int ni = 0; ni < 2; ++ni) {
      acc[mi][ni].x = 0.f; acc[mi][ni].y = 0.f;
      acc[mi][ni].z = 0.f; acc[mi][ni].w = 0.f;
    }

  bool f = false;

  for (int kt = 0; kt < D_ / 64; ++kt) {
    const int k0 = kt * 64 + scg;
    float4 xa = *(const float4*)&xrow[k0];
    float4 xb = *(const float4*)&xrow[k0 + 4];
    float4 xc = *(const float4*)&xrow[k0 + 8];
    float4 xd = *(const float4*)&xrow[k0 + 12];
    float4 wa = *(const float4*)&wrow[k0];
    float4 wb = *(const float4*)&wrow[k0 + 4];
    float4 wc = *(const float4*)&wrow[k0 + 8];
    float4 wd = *(const float4*)&wrow[k0 + 12];
    f |= (xa.x != 0.f) | (xa.y != 0.f) | (xa.z != 0.f) | (xa.w != 0.f) |
         (xb.x != 0.f) | (xb.y != 0.f) | (xb.z != 0.f) | (xb.w != 0.f) |
         (xc.x != 0.f) | (xc.y != 0.f) | (xc.z != 0.f) | (xc.w != 0.f) |
         (xd.x != 0.f) | (xd.y != 0.f) | (xd.z != 0.f) | (xd.w != 0.f);
    __syncthreads();   // previous iter's fragment reads done
    {
      f16x8 p0 = {(_Float16)xa.x, (_Float16)xa.y, (_Float16)xa.z, (_Float16)xa.w,
                  (_Float16)xb.x, (_Float16)xb.y, (_Float16)xb.z, (_Float16)xb.w};
      f16x8 p1 = {(_Float16)xc.x, (_Float16)xc.y, (_Float16)xc.z, (_Float16)xc.w,
                  (_Float16)xd.x, (_Float16)xd.y, (_Float16)xd.z, (_Float16)xd.w};
      *(f16x8*)&Xs[srow][scg] = p0;
      *(f16x8*)&Xs[srow][scg + 8] = p1;
      f16x8 q0 = {(_Float16)wa.x, (_Float16)wa.y, (_Float16)wa.z, (_Float16)wa.w,
                  (_Float16)wb.x, (_Float16)wb.y, (_Float16)wb.z, (_Float16)wb.w};
      f16x8 q1 = {(_Float16)wc.x, (_Float16)wc.y, (_Float16)wc.z, (_Float16)wc.w,
                  (_Float16)wd.x, (_Float16)wd.y, (_Float16)wd.z, (_Float16)wd.w};
      *(f16x8*)&Ws[srow][scg] = q0;
      *(f16x8*)&Ws[srow][scg + 8] = q1;
    }
    __syncthreads();
#pragma unroll
    for (int ks = 0; ks < 2; ++ks) {
      const int kb = ks * 32 + l4 * 8;
      f16x8 a0 = *(const f16x8*)&Xs[wm + l15][kb];
      f16x8 a1 = *(const f16x8*)&Xs[wm + 16 + l15][kb];
      f16x8 b0 = *(const f16x8*)&Ws[wn + l15][kb];
      f16x8 b1 = *(const f16x8*)&Ws[wn + 16 + l15][kb];
      acc[0][0] = __builtin_amdgcn_mfma_f32_16x16x32_f16(a0, b0, acc[0][0], 0, 0, 0);
      acc[0][1] = __builtin_amdgcn_mfma_f32_16x16x32_f16(a0, b1, acc[0][1], 0, 0, 0);
      acc[1][0] = __builtin_amdgcn_mfma_f32_16x16x32_f16(a1, b0, acc[1][0], 0, 0, 0);
      acc[1][1] = __builtin_amdgcn_mfma_f32_16x16x32_f16(a1, b1, acc[1][1], 0, 0, 0);
    }
  }

  // epilogue: bias + store (C/D: col = lane&15, row = (lane>>4)*4 + reg)
  const float bias0 = b0ih[c0 + wn + l15];
  const float bias1 = b0ih[c0 + wn + 16 + l15];
  const size_t rowbase = (size_t)b * Tc + tt * 64;
#pragma unroll
  for (int mi = 0; mi < 2; ++mi)
#pragma unroll
    for (int r = 0; r < 4; ++r) {
      const int m = wm + mi * 16 + l4 * 4 + r;
      float* orow = &gi0[(rowbase + m) * N3 + c0 + wn];
      orow[l15]      = acc[mi][0][r] + bias0;
      orow[16 + l15] = acc[mi][1][r] + bias1;
    }

  if (tid < 64) sflag[tid] = 0;
  __syncthreads();
  if (f) sflag[srow] = 1;
  __syncthreads();
  if (tid < 64 && sflag[tid]) act[t0 + tt * 64 + tid] = 1;
}

// ------------- pass 2: LAYER-PIPELINED scan (unchanged from round 14, 397us) -------------
__global__ __launch_bounds__(640) void scan_kernel(
    const float* __restrict__ gi0,   // [B,Tc,N3]
    const float* __restrict__ w0hh, const float* __restrict__ w1ih,
    const float* __restrict__ w1hh, const float* __restrict__ w2ih,
    const float* __restrict__ w2hh,
    const float* __restrict__ b0hh, const float* __restrict__ b1ih,
    const float* __restrict__ b1hh, const float* __restrict__ b2ih,
    const float* __restrict__ b2hh,
    const int* __restrict__ act,     // [T]
    float* __restrict__ hstate,      // [3,B,H]
    float* __restrict__ out,         // [B,T,H]
    int t0, int Tc) {
  const int b   = blockIdx.x;
  const int tid = threadIdx.x;

  __shared__ __align__(16) int4 s_w[3][192][8];       // 73728 B
  __shared__ __align__(16) _Float16 s_h[3][2][H_];    // [layer][parity][unit]
  __shared__ int s_act[T_];

  {
    const float* wsrc[3] = {w0hh, w1hh, w2hh};
    for (int i = tid; i < 3 * 192 * 8; i += 640) {
      int m = i / 1536;
      int rem = i - m * 1536;
      int row = rem >> 3;
      int c = rem & 7;
      const float* sp = wsrc[m] + (size_t)row * H_ + 8 * c;
      float4 lo = *(const float4*)sp;
      float4 hi = *(const float4*)(sp + 4);
      h2v p0 = {(_Float16)lo.x, (_Float16)lo.y};
      h2v p1 = {(_Float16)lo.z, (_Float16)lo.w};
      h2v p2 = {(_Float16)hi.x, (_Float16)hi.y};
      h2v p3 = {(_Float16)hi.z, (_Float16)hi.w};
      int4 pk;
      pk.x = __builtin_bit_cast(int, p0);
      pk.y = __builtin_bit_cast(int, p1);
      pk.z = __builtin_bit_cast(int, p2);
      pk.w = __builtin_bit_cast(int, p3);
      s_w[m][row][c ^ (row & 7)] = pk;
    }
  }
  for (int i = tid; i < Tc; i += 640) s_act[i] = act[t0 + i];

  const int grp = (tid < 128) ? 0 : (tid < 384) ? 1 : 2;
  const int lt  = tid - ((grp == 0) ? 0 : (grp == 1) ? 128 : 384);
  const int jj  = (grp == 0) ? (lt >> 1) : (lt >> 2);
  const int gg  = (grp == 0) ? (lt & 1) : (lt & 3);
  const int swz = jj & 7;

  if (tid < H_) {
    float v0 = (t0 == 0) ? 0.f : hstate[0 * B_ * H_ + b * H_ + tid];
    float v1 = (t0 == 0) ? 0.f : hstate[1 * B_ * H_ + b * H_ + tid];
    float v2 = (t0 == 0) ? 0.f : hstate[2 * B_ * H_ + b * H_ + tid];
    s_h[0][0][tid] = (_Float16)v0; s_h[0][1][tid] = (_Float16)v0;
    s_h[1][0][tid] = (_Float16)v1; s_h[1][1][tid] = (_Float16)v1;
    s_h[2][0][tid] = (_Float16)v2; s_h[2][1][tid] = (_Float16)v2;
  }
  float hreg = (t0 == 0) ? 0.f : hstate[grp * B_ * H_ + b * H_ + jj];

  int rpk[3][8];
  {
    const float* ihsrc = (grp == 2) ? w2ih : w1ih;
    const int lg = (grp == 0) ? (gg * 2) : gg;
#pragma unroll
    for (int r = 0; r < 3; ++r) {
      const float* src = ihsrc + (size_t)(jj + 64 * r) * H_ + 16 * lg;
#pragma unroll
      for (int q = 0; q < 8; ++q) {
        float2 fv = *(const float2*)(src + 2 * q);
        h2v pv = {(_Float16)fv.x, (_Float16)fv.y};
        rpk[r][q] = __builtin_bit_cast(int, pv);
      }
    }
#pragma unroll
    for (int r = 0; r < 3; ++r)
#pragma unroll
      for (int q = 0; q < 8; ++q) KEEP(rpk[r][q]);
  }

  float bsv[4];
  if (grp == 0) {
    bsv[0] = b0hh[jj]; bsv[1] = b0hh[jj + 64]; bsv[2] = 0.f;
    bsv[3] = b0hh[jj + 128];
  } else if (grp == 1) {
    bsv[0] = b1ih[jj] + b1hh[jj];
    bsv[1] = b1ih[jj + 64] + b1hh[jj + 64];
    bsv[2] = b1ih[jj + 128]; bsv[3] = b1hh[jj + 128];
  } else {
    bsv[0] = b2ih[jj] + b2hh[jj];
    bsv[1] = b2ih[jj + 64] + b2hh[jj + 64];
    bsv[2] = b2ih[jj + 128]; bsv[3] = b2hh[jj + 128];
  }

  const float* gib = gi0 + (size_t)b * Tc * N3;
  float giR = 0.f, giZ = 0.f, giN = 0.f;
  if (grp == 0) { giR = gib[jj]; giZ = gib[jj + 64]; giN = gib[jj + 128]; }

  __syncthreads();

  for (int i = 0; i < Tc + 2; ++i) {
    const int p = i & 1;
    if (grp == 0) {
      if (i < Tc) {
        const int4* hp = (const int4*)s_h[0][p ^ 1];
        int4 h0s = hp[4 * gg + 0], h1s = hp[4 * gg + 1];
        int4 h2s = hp[4 * gg + 2], h3s = hp[4 * gg + 3];
        float R0 = 0, R1 = 0, Z0 = 0, Z1 = 0, N0 = 0, N1 = 0;
#pragma unroll
        for (int k = 0; k < 4; ++k) {
          int pc = (4 * gg + k) ^ swz;
          int4 hk = (k == 0) ? h0s : (k == 1) ? h1s : (k == 2) ? h2s : h3s;
          dot4acc(s_w[0][jj][pc],       hk, R0, R1);
          dot4acc(s_w[0][jj + 64][pc],  hk, Z0, Z1);
          dot4acc(s_w[0][jj + 128][pc], hk, N0, N1);
        }
        float dR = red2(R0 + R1) + bsv[0];
        float dZ = red2(Z0 + Z1) + bsv[1];
        float dN = red2(N0 + N1) + bsv[3];
        bool a = (s_act[i] != 0);
        float r = sigm_f(giR + dR);
        float z = sigm_f(giZ + dZ);
        float n = tanh_f(giN + r * dN);
        float hn = (1.0f - z) * n + z * hreg;
        hreg = a ? hn : hreg;
        if (gg == 0) s_h[0][p][jj] = (_Float16)hreg;
        int tn = (i + 1 < Tc) ? i + 1 : i;
        giR = gib[(size_t)tn * N3 + jj];
        giZ = gib[(size_t)tn * N3 + jj + 64];
        giN = gib[(size_t)tn * N3 + jj + 128];
      }
    } else if (grp == 1) {
      if (i >= 1 && i <= Tc) {
        const int4* h0p = (const int4*)s_h[0][p ^ 1];
        const int4* h1p = (const int4*)s_h[1][p ^ 1];
        int4 x0 = h0p[2 * gg], x1 = h0p[2 * gg + 1];
        int4 y0 = h1p[2 * gg], y1 = h1p[2 * gg + 1];
        float vR0 = 0, vR1 = 0, vZ0 = 0, vZ1 = 0;
        float iN0 = 0, iN1 = 0, hN0 = 0, hN1 = 0;
        dot8reg(rpk[0], x0, x1, vR0, vR1);
        dot8reg(rpk[1], x0, x1, vZ0, vZ1);
        dot8reg(rpk[2], x0, x1, iN0, iN1);
        int pc0 = (2 * gg) ^ swz, pc1 = (2 * gg + 1) ^ swz;
        dot4acc(s_w[1][jj][pc0],       y0, vR0, vR1);
        dot4acc(s_w[1][jj][pc1],       y1, vR0, vR1);
        dot4acc(s_w[1][jj + 64][pc0],  y0, vZ0, vZ1);
        dot4acc(s_w[1][jj + 64][pc1],  y1, vZ0, vZ1);
        dot4acc(s_w[1][jj + 128][pc0], y0, hN0, hN1);
        dot4acc(s_w[1][jj + 128][pc1], y1, hN0, hN1);
        float sR = red4(vR0 + vR1) + bsv[0];
        float sZ = red4(vZ0 + vZ1) + bsv[1];
        float iN = red4(iN0 + iN1) + bsv[2];
        float hN = red4(hN0 + hN1) + bsv[3];
        bool a = (s_act[i - 1] != 0);
        float r = sigm_f(sR);
        float z = sigm_f(sZ);
        float n = tanh_f(iN + r * hN);
        float hn = (1.0f - z) * n + z * hreg;
        hreg = a ? hn : hreg;
        if (gg == 0) s_h[1][p][jj] = (_Float16)hreg;
      }
    } else {
      if (i >= 2) {
        const int4* h1p = (const int4*)s_h[1][p ^ 1];
        const int4* h2p = (const int4*)s_h[2][p ^ 1];
        int4 x0 = h1p[2 * gg], x1 = h1p[2 * gg + 1];
        int4 y0 = h2p[2 * gg], y1 = h2p[2 * gg + 1];
        float vR0 = 0, vR1 = 0, vZ0 = 0, vZ1 = 0;
        float iN0 = 0, iN1 = 0, hN0 = 0, hN1 = 0;
        dot8reg(rpk[0], x0, x1, vR0, vR1);
        dot8reg(rpk[1], x0, x1, vZ0, vZ1);
        dot8reg(rpk[2], x0, x1, iN0, iN1);
        int pc0 = (2 * gg) ^ swz, pc1 = (2 * gg + 1) ^ swz;
        dot4acc(s_w[2][jj][pc0],       y0, vR0, vR1);
        dot4acc(s_w[2][jj][pc1],       y1, vR0, vR1);
        dot4acc(s_w[2][jj + 64][pc0],  y0, vZ0, vZ1);
        dot4acc(s_w[2][jj + 64][pc1],  y1, vZ0, vZ1);
        dot4acc(s_w[2][jj + 128][pc0], y0, hN0, hN1);
        dot4acc(s_w[2][jj + 128][pc1], y1, hN0, hN1);
        float sR = red4(vR0 + vR1) + bsv[0];
        float sZ = red4(vZ0 + vZ1) + bsv[1];
        float iN = red4(iN0 + iN1) + bsv[2];
        float hN = red4(hN0 + hN1) + bsv[3];
        bool a = (s_act[i - 2] != 0);
        float r = sigm_f(sR);
        float z = sigm_f(sZ);
        float n = tanh_f(iN + r * hN);
        float hn = (1.0f - z) * n + z * hreg;
        hreg = a ? hn : hreg;
        if (gg == 0) {
          s_h[2][p][jj] = (_Float16)hreg;
          out[((size_t)b * T_ + t0 + (i - 2)) * H_ + jj] = a ? hreg : 0.0f;
        }
      }
    }
    __syncthreads();
  }

  if (gg == 0) hstate[grp * B_ * H_ + b * H_ + jj] = hreg;
}

extern "C" void kernel_launch(void* const* d_in, const int* in_sizes, int n_in,
                              void* d_out, int out_size, void* d_ws, size_t ws_size,
                              hipStream_t stream) {
  const float* x    = (const float*)d_in[0];
  const float* w0ih = (const float*)d_in[1];
  const float* w0hh = (const float*)d_in[2];
  const float* b0ih = (const float*)d_in[3];
  const float* b0hh = (const float*)d_in[4];
  const float* w1ih = (const float*)d_in[5];
  const float* w1hh = (const float*)d_in[6];
  const float* b1ih = (const float*)d_in[7];
  const float* b1hh = (const float*)d_in[8];
  const float* w2ih = (const float*)d_in[9];
  const float* w2hh = (const float*)d_in[10];
  const float* b2ih = (const float*)d_in[11];
  const float* b2hh = (const float*)d_in[12];
  float* out = (float*)d_out;

  char* p = (char*)d_ws;
  int* act      = (int*)p;    p += 4096;
  float* hstate = (float*)p;  p += (size_t)3 * B_ * H_ * 4;
  size_t fixed = (size_t)(p - (char*)d_ws);

  int Tc = T_;
  while (Tc > 64 && fixed + (size_t)B_ * Tc * N3 * 4 > ws_size) Tc >>= 1;
  float* gi0 = (float*)p;

  hipMemsetAsync(act, 0, T_ * sizeof(int), stream);
  for (int t0 = 0; t0 < T_; t0 += Tc) {
    gemm_kernel<<<dim3(B_ * (Tc / 64) * 3), 256, 0, stream>>>(
        x, w0ih, b0ih, gi0, act, t0, Tc);
    scan_kernel<<<B_, 640, 0, stream>>>(
        gi0, w0hh, w1ih, w1hh, w2ih, w2hh,
        b0hh, b1ih, b1hh, b2ih, b2hh, act, hstate, out, t0, Tc);
  }
}